// Round 1
// baseline (744.999 us; speedup 1.0000x reference)
//
#include <hip/hip_runtime.h>
#include <hip/hip_bf16.h>

constexpr int Ej  = 294912;  // total edges
constexpr int EPG = 1152;    // edges per graph
constexpr int WC2 = 144;     // fused-GEMM cols per head: A64 | V64 | r8:8 | cD | cS | pad6

typedef __attribute__((ext_vector_type(8))) short short8;   // 8 bf16 (MFMA A/B frag)
typedef __attribute__((ext_vector_type(4))) float f32x4;    // MFMA C/D frag

// monotone float<->uint encoding for atomicMax on floats
__device__ __forceinline__ unsigned encf(float f) {
  unsigned u = __float_as_uint(f);
  return (u & 0x80000000u) ? ~u : (u | 0x80000000u);
}
__device__ __forceinline__ float decf(unsigned u) {
  return (u & 0x80000000u) ? __uint_as_float(u & 0x7FFFFFFFu) : __uint_as_float(~u);
}
// fp32 -> bf16 bits, round-to-nearest-even
__device__ __forceinline__ unsigned short f2bf(float f) {
  unsigned u = __float_as_uint(f);
  u += 0x7FFFu + ((u >> 16) & 1u);
  return (unsigned short)(u >> 16);
}
// 64-lane sum via DPP. Result valid in lane 63.
__device__ __forceinline__ float wave_red_sum(float x) {
  x += __int_as_float(__builtin_amdgcn_update_dpp(0, __float_as_int(x), 0x111, 0xf, 0xf, true));
  x += __int_as_float(__builtin_amdgcn_update_dpp(0, __float_as_int(x), 0x112, 0xf, 0xf, true));
  x += __int_as_float(__builtin_amdgcn_update_dpp(0, __float_as_int(x), 0x114, 0xf, 0xf, true));
  x += __int_as_float(__builtin_amdgcn_update_dpp(0, __float_as_int(x), 0x118, 0xf, 0xf, true));
  x += __int_as_float(__builtin_amdgcn_update_dpp(0, __float_as_int(x), 0x142, 0xf, 0xf, true));
  x += __int_as_float(__builtin_amdgcn_update_dpp(0, __float_as_int(x), 0x143, 0xf, 0xf, true));
  return x;
}

// G[l][h][a][c] = sum_d W_edge[a,d]*We_l[d][h64+c];  bb[l][h][c] = be + b_edge@We  (unchanged)
__global__ void k_prep2(const float* __restrict__ We, const float* __restrict__ be,
                        const float* __restrict__ W_edge, const float* __restrict__ b_edge,
                        float* __restrict__ G, float* __restrict__ bb) {
  int tid = blockIdx.x * 256 + threadIdx.x;  // 8192 + 1024
  if (tid < 8192) {
    int l = tid >> 11, rem = tid & 2047;
    int hh = rem >> 9, a = (rem >> 6) & 7, c = rem & 63;
    float acc = 0.f;
#pragma unroll 8
    for (int d = 0; d < 64; ++d)
      acc += W_edge[a * 64 + d] * We[l * 16384 + d * 256 + hh * 64 + c];
    G[tid] = acc;
  } else if (tid < 9216) {
    int t = tid - 8192;
    int l = t >> 8, rem = t & 255;
    int hh = rem >> 6, c = rem & 63;
    float acc = be[l * 256 + hh * 64 + c];
#pragma unroll 8
    for (int d = 0; d < 64; ++d)
      acc += b_edge[d] * We[l * 16384 + d * 256 + hh * 64 + c];
    bb[t] = acc;
  }
}

// WcatT [lh][col][kk] bf16 + bcatT fp32.
// col<64:   A  = 0.125*(Wq_h @ Wk_h^T)[kk][col], bias 0                 (scores via A@hB^T)
// col<128:  V  = Wv, bias bv
// col<136:  r8 = 0.125*Wq_h@G[a]^T, bias 0.125*bq_h.G[a]
// col==136: cD = 0.125*Wq_h@(bk+bb)^T, bias 0.125*bq.(bk+bb)   (per-dst scalar)
// col==137: cS = 0.125*Wk_h@bq^T, bias 0                        (per-src scalar)
__global__ void __launch_bounds__(256) k_prepW(
    const float* __restrict__ Wq, const float* __restrict__ bq,
    const float* __restrict__ Wk, const float* __restrict__ bk,
    const float* __restrict__ Wv, const float* __restrict__ bv,
    const float* __restrict__ Gbuf, const float* __restrict__ bbuf,
    unsigned short* __restrict__ WcatT, float* __restrict__ bcatT) {
  int t = blockIdx.x * 256 + threadIdx.x;  // 16*144*64
  if (t >= 16 * WC2 * 64) return;
  int kk = t & 63;
  int col = (t >> 6) % WC2;
  int lh = t / (WC2 * 64);
  int h = lh & 3, l = lh >> 2;
  const float* Wq_l = Wq + l * 16384;
  const float* Wk_l = Wk + l * 16384;
  const float* bq_l = bq + l * 256;
  const float* bk_l = bk + l * 256;
  float w = 0.f, bias = 0.f;
  if (col < 64) {
    float s = 0.f;
#pragma unroll 8
    for (int i = 0; i < 64; ++i)
      s += Wq_l[kk * 256 + h * 64 + i] * Wk_l[col * 256 + h * 64 + i];
    w = 0.125f * s;
  } else if (col < 128) {
    int j = col - 64;
    w = Wv[l * 16384 + kk * 256 + h * 64 + j];
    bias = bv[l * 256 + h * 64 + j];
  } else if (col < 136) {
    int a = col - 128;
    const float* Grow = Gbuf + l * 2048 + h * 512 + a * 64;
    float s = 0.f, sb = 0.f;
#pragma unroll 8
    for (int i = 0; i < 64; ++i) {
      s  += Wq_l[kk * 256 + h * 64 + i] * Grow[i];
      sb += bq_l[h * 64 + i] * Grow[i];
    }
    w = 0.125f * s; bias = 0.125f * sb;
  } else if (col == 136) {
    float s = 0.f, sb = 0.f;
#pragma unroll 8
    for (int i = 0; i < 64; ++i) {
      float bkb = bk_l[h * 64 + i] + bbuf[l * 256 + h * 64 + i];
      s  += Wq_l[kk * 256 + h * 64 + i] * bkb;
      sb += bq_l[h * 64 + i] * bkb;
    }
    w = 0.125f * s; bias = 0.125f * sb;
  } else if (col == 137) {
    float s = 0.f;
#pragma unroll 8
    for (int i = 0; i < 64; ++i)
      s += Wk_l[kk * 256 + h * 64 + i] * bq_l[h * 64 + i];
    w = 0.125f * s;
  }
  WcatT[(size_t)(lh * WC2 + col) * 64 + kk] = f2bf(w);
  if (kk == 0) bcatT[lh * WC2 + col] = bias;
}

// One block per graph: node_enc + 4 layers x (4 heads x attention) x fused update + head.
// h resident in LDS fp32 (stride 68). agg accumulated across heads in MFMA C registers.
// Per-edge state (src/dst, ea[8], alpha) in registers across P2..P4.
// LDS total 155136 B -> 1 block/CU, 16 waves.
__global__ void __launch_bounds__(1024, 4) k_fused(
    const float* __restrict__ x, const float* __restrict__ W_node, const float* __restrict__ b_node,
    const unsigned short* __restrict__ WcatT, const float* __restrict__ bcatT,
    const float* __restrict__ edge_attr, const int* __restrict__ ei,
    const float* __restrict__ Gbuf, const float* __restrict__ bbuf,
    const float* __restrict__ Wskip, const float* __restrict__ bskip,
    const float* __restrict__ Wd, const float* __restrict__ bd,
    const float* __restrict__ Wo, const float* __restrict__ bo,
    float* __restrict__ out) {
  __shared__ float SS[16384];              // 65536 B: WT stage | scores (swizzled) | Wmat bf16 | Wskip
  __shared__ float h32[128 * 68];          // 34816 B: resident fp32 h
  __shared__ unsigned short hB[128 * 80];  // 20480 B: bf16 h (per-layer)
  __shared__ unsigned short AV[128 * 80];  // 20480 B: A-matrix (P0-P1), then Vt bf16 64x136 (P2-P5)
  __shared__ float r8L[128 * 8];           // 4096
  __shared__ float t8L[128 * 9];           // 4608
  __shared__ unsigned mL[128];             // 512
  __shared__ float sL[128];                // 512
  __shared__ float cDL[128];               // 512
  __shared__ float cSL[128];               // 512
  __shared__ float GhL[512];               // 2048
  __shared__ float vembL[256];             // 1024

  int g = blockIdx.x, tid = threadIdx.x;
  int lane = tid & 63, m16 = lane & 15, quad = lane >> 4, wv = tid >> 6;

  // prefetch WT for (l=0,h=0) into regs (consumed at first stage)
  uint4 wpA = ((const uint4*)WcatT)[tid];
  uint4 wpB;
  if (tid < 128) wpB = ((const uint4*)WcatT)[1024 + tid];

  // node encoder -> h32
  for (int idx = tid; idx < 8192; idx += 1024) {
    int n = idx >> 6, c = idx & 63;
    const float* xr = x + (size_t)(g * 128 + n) * 16;
    float acc = b_node[c];
#pragma unroll
    for (int d = 0; d < 16; ++d) acc += xr[d] * W_node[d * 64 + c];
    h32[n * 68 + c] = acc;
  }

  // per-edge registers: edge A = tid, edge B = 1024+tid (tid<128)
  const float* eaG = edge_attr + (size_t)g * EPG * 8;
  int edA, edB = 0;
  float4 eaA0, eaA1;
  float4 eaB0 = make_float4(0, 0, 0, 0), eaB1 = make_float4(0, 0, 0, 0);
  {
    int s = ei[g * EPG + tid] - g * 128;
    int d = ei[Ej + g * EPG + tid] - g * 128;
    edA = s | (d << 8);
    eaA0 = *(const float4*)(eaG + (size_t)tid * 8);
    eaA1 = *(const float4*)(eaG + (size_t)tid * 8 + 4);
  }
  bool hasB = tid < (EPG - 1024);
  if (hasB) {
    int e = 1024 + tid;
    int s = ei[g * EPG + e] - g * 128;
    int d = ei[Ej + g * EPG + e] - g * 128;
    edB = s | (d << 8);
    eaB0 = *(const float4*)(eaG + (size_t)e * 8);
    eaB1 = *(const float4*)(eaG + (size_t)e * 8 + 4);
  }
  __syncthreads();

  for (int l = 0; l < 4; ++l) {
    // stage hB = bf16(h32)
    {
      int n8 = tid >> 3, c8 = tid & 7;
      const float* hr = &h32[n8 * 68 + c8 * 8];
      float4 a0 = *(const float4*)hr, a1 = *(const float4*)(hr + 4);
      uint4 hp;
      hp.x = f2bf(a0.x) | ((unsigned)f2bf(a0.y) << 16);
      hp.y = f2bf(a0.z) | ((unsigned)f2bf(a0.w) << 16);
      hp.z = f2bf(a1.x) | ((unsigned)f2bf(a1.y) << 16);
      hp.w = f2bf(a1.z) | ((unsigned)f2bf(a1.w) << 16);
      *(uint4*)&hB[n8 * 80 + c8 * 8] = hp;
    }
    f32x4 accP5[2];
    accP5[0] = (f32x4){0.f, 0.f, 0.f, 0.f};
    accP5[1] = (f32x4){0.f, 0.f, 0.f, 0.f};
    float4 wskpre;

    for (int h = 0; h < 4; ++h) {
      __syncthreads();  // prev head's P5 / layer-top hB stage complete
      // ---- stage: WT (from prefetch regs) into SS, GhL, zero mL/sL/t8L
      {
        unsigned short* WT = (unsigned short*)SS;
        ((uint4*)WT)[tid] = wpA;
        if (tid < 128) ((uint4*)WT)[1024 + tid] = wpB;
      }
      for (int idx = tid; idx < 512; idx += 1024) GhL[idx] = Gbuf[l * 2048 + h * 512 + idx];
      if (tid < 128) { mL[tid] = 0u; sL[tid] = 0.f; }
      for (int idx = tid; idx < 1152; idx += 1024) t8L[idx] = 0.f;
      __syncthreads();

      // ---- P0: fused GEMM out[node][col] = hB @ WT^T + bias. 72 tiles (8m x 9n).
      const unsigned short* WT = (const unsigned short*)SS;
      const float* bcTl = bcatT + (l * 4 + h) * WC2;
      f32x4 vfrag[2];
      int vc[2], vm[2], vcount = 0;
      for (int t = wv; t < 72; t += 16) {
        int m0 = (t & 7) * 16, n0 = (t >> 3) * 16;
        const short8 a0 = *(const short8*)&hB[(m0 + m16) * 80 + quad * 8];
        const short8 a1 = *(const short8*)&hB[(m0 + m16) * 80 + 32 + quad * 8];
        const short8 b0 = *(const short8*)&WT[(n0 + m16) * 64 + quad * 8];
        const short8 b1 = *(const short8*)&WT[(n0 + m16) * 64 + 32 + quad * 8];
        float bias = bcTl[n0 + m16];
        f32x4 acc = {bias, bias, bias, bias};
        acc = __builtin_amdgcn_mfma_f32_16x16x32_bf16(a0, b0, acc, 0, 0, 0);
        acc = __builtin_amdgcn_mfma_f32_16x16x32_bf16(a1, b1, acc, 0, 0, 0);
        if (n0 < 64) {
#pragma unroll
          for (int r = 0; r < 4; ++r)
            AV[(m0 + quad * 4 + r) * 80 + n0 + m16] = f2bf(acc[r]);
        } else if (n0 < 128) {
          vfrag[vcount] = acc; vm[vcount] = m0; vc[vcount] = n0 - 64; ++vcount;
        } else {
          if (m16 < 8) {
#pragma unroll
            for (int r = 0; r < 4; ++r) r8L[(m0 + quad * 4 + r) * 8 + m16] = acc[r];
          } else if (m16 == 8) {
#pragma unroll
            for (int r = 0; r < 4; ++r) cDL[m0 + quad * 4 + r] = acc[r];
          } else if (m16 == 9) {
#pragma unroll
            for (int r = 0; r < 4; ++r) cSL[m0 + quad * 4 + r] = acc[r];
          }
        }
      }
      __syncthreads();

      // ---- P1: scores = A @ hB^T -> SS fp32, col XOR-swizzled per row
      {
        int strip = wv >> 1, halfw = wv & 1, dst0 = strip * 16;
        const short8 a0 = *(const short8*)&AV[(dst0 + m16) * 80 + quad * 8];
        const short8 a1 = *(const short8*)&AV[(dst0 + m16) * 80 + 32 + quad * 8];
#pragma unroll
        for (int t = 0; t < 4; ++t) {
          int src0 = (halfw * 4 + t) * 16;
          const short8 b0 = *(const short8*)&hB[(src0 + m16) * 80 + quad * 8];
          const short8 b1 = *(const short8*)&hB[(src0 + m16) * 80 + 32 + quad * 8];
          f32x4 acc = {0.f, 0.f, 0.f, 0.f};
          acc = __builtin_amdgcn_mfma_f32_16x16x32_bf16(a0, b0, acc, 0, 0, 0);
          acc = __builtin_amdgcn_mfma_f32_16x16x32_bf16(a1, b1, acc, 0, 0, 0);
#pragma unroll
          for (int r = 0; r < 4; ++r) {
            int row = dst0 + quad * 4 + r;
            SS[row * 128 + ((src0 + m16) ^ ((row & 7) << 4))] = acc[r];
          }
        }
      }
      __syncthreads();

      // ---- P2: deposit v frags -> Vt (AV region, bf16, transposed); alpha + segment max
#pragma unroll
      for (int i = 0; i < 2; ++i) {
        int col = vc[i] + m16;
#pragma unroll
        for (int r = 0; r < 4; ++r)
          AV[col * 136 + vm[i] + quad * 4 + r] = f2bf(vfrag[i][r]);
      }
      float aA, aB = 0.f;
      {
        int src = edA & 255, dst = edA >> 8;
        float4 r80 = *(const float4*)&r8L[dst * 8];
        float4 r81 = *(const float4*)&r8L[dst * 8 + 4];
        aA = SS[dst * 128 + (src ^ ((dst & 7) << 4))] + cDL[dst] + cSL[src]
           + eaA0.x * r80.x + eaA0.y * r80.y + eaA0.z * r80.z + eaA0.w * r80.w
           + eaA1.x * r81.x + eaA1.y * r81.y + eaA1.z * r81.z + eaA1.w * r81.w;
        atomicMax(&mL[dst], encf(aA));
      }
      if (hasB) {
        int src = edB & 255, dst = edB >> 8;
        float4 r80 = *(const float4*)&r8L[dst * 8];
        float4 r81 = *(const float4*)&r8L[dst * 8 + 4];
        aB = SS[dst * 128 + (src ^ ((dst & 7) << 4))] + cDL[dst] + cSL[src]
           + eaB0.x * r80.x + eaB0.y * r80.y + eaB0.z * r80.z + eaB0.w * r80.w
           + eaB1.x * r81.x + eaB1.y * r81.y + eaB1.z * r81.z + eaB1.w * r81.w;
        atomicMax(&mL[dst], encf(aB));
      }
      __syncthreads();

      // ---- P3: zero SS; exp + segment sum (alpha stays in regs)
      for (int idx = tid; idx < 4096; idx += 1024)
        *(float4*)&SS[idx * 4] = make_float4(0.f, 0.f, 0.f, 0.f);
      {
        int dst = edA >> 8;
        aA = expf(aA - decf(mL[dst]));
        atomicAdd(&sL[dst], aA);
      }
      if (hasB) {
        int dst = edB >> 8;
        aB = expf(aB - decf(mL[dst]));
        atomicAdd(&sL[dst], aB);
      }
      __syncthreads();

      // ---- P4: scatter normalized weights into Wmat(fp32, swizzled); accumulate t8
      {
        int src = edA & 255, dst = edA >> 8;
        float w = aA / fmaxf(sL[dst], 1e-16f);
        atomicAdd(&SS[dst * 128 + (src ^ ((dst & 7) << 4))], w);
        float* t8 = &t8L[dst * 9];
        atomicAdd(t8 + 0, w * eaA0.x); atomicAdd(t8 + 1, w * eaA0.y);
        atomicAdd(t8 + 2, w * eaA0.z); atomicAdd(t8 + 3, w * eaA0.w);
        atomicAdd(t8 + 4, w * eaA1.x); atomicAdd(t8 + 5, w * eaA1.y);
        atomicAdd(t8 + 6, w * eaA1.z); atomicAdd(t8 + 7, w * eaA1.w);
      }
      if (hasB) {
        int src = edB & 255, dst = edB >> 8;
        float w = aB / fmaxf(sL[dst], 1e-16f);
        atomicAdd(&SS[dst * 128 + (src ^ ((dst & 7) << 4))], w);
        float* t8 = &t8L[dst * 9];
        atomicAdd(t8 + 0, w * eaB0.x); atomicAdd(t8 + 1, w * eaB0.y);
        atomicAdd(t8 + 2, w * eaB0.z); atomicAdd(t8 + 3, w * eaB0.w);
        atomicAdd(t8 + 4, w * eaB1.x); atomicAdd(t8 + 5, w * eaB1.y);
        atomicAdd(t8 + 6, w * eaB1.z); atomicAdd(t8 + 7, w * eaB1.w);
      }
      __syncthreads();

      // ---- P4.5: repack Wmat fp32(swizzled) -> bf16 stride 136 in place
      {
        float vals[16];
        int i0 = tid * 16;
        int dst = i0 >> 7, src0 = i0 & 127;
        int base = dst * 128 + (src0 ^ ((dst & 7) << 4));
#pragma unroll
        for (int i = 0; i < 16; ++i) vals[i] = SS[base + i];
        __syncthreads();
        unsigned short* Wu = (unsigned short*)SS;
#pragma unroll
        for (int g4 = 0; g4 < 2; ++g4) {
          uint4 u;
          u.x = f2bf(vals[g4 * 8 + 0]) | ((unsigned)f2bf(vals[g4 * 8 + 1]) << 16);
          u.y = f2bf(vals[g4 * 8 + 2]) | ((unsigned)f2bf(vals[g4 * 8 + 3]) << 16);
          u.z = f2bf(vals[g4 * 8 + 4]) | ((unsigned)f2bf(vals[g4 * 8 + 5]) << 16);
          u.w = f2bf(vals[g4 * 8 + 6]) | ((unsigned)f2bf(vals[g4 * 8 + 7]) << 16);
          *(uint4*)&Wu[dst * 136 + src0 + g4 * 8] = u;
        }
      }
      __syncthreads();

      // ---- P5: accP5 += Wmat@Vt (MFMA) + t8@G + sw*bb ; prefetch next WT / Wskip
      {
        int nlh = l * 4 + h + 1;
        if (nlh < 16) {
          const uint4* wsrc = (const uint4*)(WcatT + (size_t)nlh * (WC2 * 64));
          wpA = wsrc[tid];
          if (tid < 128) wpB = wsrc[1024 + tid];
        }
        if (h == 3) wskpre = ((const float4*)(Wskip + (size_t)l * 4096))[tid];

        const unsigned short* Wu = (const unsigned short*)SS;
        int strip = wv >> 1, halfc = wv & 1, dst0 = strip * 16;
        short8 a[4];
#pragma unroll
        for (int ks = 0; ks < 4; ++ks)
          a[ks] = *(const short8*)&Wu[(dst0 + m16) * 136 + ks * 32 + quad * 8];
#pragma unroll
        for (int t2 = 0; t2 < 2; ++t2) {
          int c0 = (halfc * 2 + t2) * 16;
          f32x4 acc = accP5[t2];
#pragma unroll
          for (int ks = 0; ks < 4; ++ks) {
            const short8 b = *(const short8*)&AV[(c0 + m16) * 136 + ks * 32 + quad * 8];
            acc = __builtin_amdgcn_mfma_f32_16x16x32_bf16(a[ks], b, acc, 0, 0, 0);
          }
          int col = c0 + m16;
          float bbv = bbuf[l * 256 + h * 64 + col];
          float gcol[8];
#pragma unroll
          for (int a8 = 0; a8 < 8; ++a8) gcol[a8] = GhL[a8 * 64 + col];
#pragma unroll
          for (int r = 0; r < 4; ++r) {
            int row = dst0 + quad * 4 + r;
            float add = (sL[row] > 0.f) ? bbv : 0.f;
#pragma unroll
            for (int a8 = 0; a8 < 8; ++a8) add += t8L[row * 9 + a8] * gcol[a8];
            acc[r] += add;
          }
          accP5[t2] = acc;
        }
      }
    }  // heads

    // ---- update: out = 0.25*acc + h@Wskip+bskip ; vemb ; h += out (all in LDS)
    __syncthreads();
    *(float4*)&SS[tid * 4] = wskpre;  // Wskip_l staged to SS[0..4096)
    __syncthreads();
    {
      int strip = wv >> 1, halfc = wv & 1, dst0 = strip * 16;
      float sk[2][4];
#pragma unroll
      for (int t2 = 0; t2 < 2; ++t2) {
        int col = halfc * 32 + t2 * 16 + m16;
        float bsv = bskip[l * 64 + col];
#pragma unroll
        for (int r = 0; r < 4; ++r) {
          int row = dst0 + quad * 4 + r;
          float s = bsv;
#pragma unroll 8
          for (int d = 0; d < 64; ++d) s += h32[row * 68 + d] * SS[d * 64 + col];
          sk[t2][r] = s;
        }
      }
      __syncthreads();  // all h32 reads done before in-place writes
#pragma unroll
      for (int t2 = 0; t2 < 2; ++t2) {
        int col = halfc * 32 + t2 * 16 + m16;
#pragma unroll
        for (int r = 0; r < 4; ++r) {
          int row = dst0 + quad * 4 + r;
          float outv = accP5[t2][r] * 0.25f + sk[t2][r];
          float hnew = outv + h32[row * 68 + col];
          h32[row * 68 + col] = hnew;
          if (row == 127) vembL[l * 64 + col] = outv;
        }
      }
    }
    __syncthreads();
  }  // layers

  // ---- head: pool = vemb @ W_down + b_down; out = sigmoid(pool @ W_out + b_out)
  {
    float part = 0.f;
#pragma unroll
    for (int j2 = 0; j2 < 16; ++j2) {
      int j = wv * 16 + j2;
      part += vembL[j] * Wd[j * 64 + lane];
    }
    SS[wv * 64 + lane] = part;
    __syncthreads();
    if (wv == 0) {
      float acc = bd[lane];
#pragma unroll
      for (int w2 = 0; w2 < 16; ++w2) acc += SS[w2 * 64 + lane];
      float p = acc * Wo[lane];
      p = wave_red_sum(p);
      if (lane == 63) out[g] = 1.f / (1.f + expf(-(p + bo[0])));
    }
  }
}

extern "C" void kernel_launch(void* const* d_in, const int* in_sizes, int n_in,
                              void* d_out, int out_size, void* d_ws, size_t ws_size,
                              hipStream_t stream) {
  const float* x         = (const float*)d_in[0];
  const float* edge_attr = (const float*)d_in[1];
  const int*   ei        = (const int*)d_in[2];
  const float* W_node = (const float*)d_in[4];
  const float* b_node = (const float*)d_in[5];
  const float* W_edge = (const float*)d_in[6];
  const float* b_edge = (const float*)d_in[7];
  const float* Wq = (const float*)d_in[8];
  const float* bq = (const float*)d_in[9];
  const float* Wk = (const float*)d_in[10];
  const float* bk = (const float*)d_in[11];
  const float* Wv = (const float*)d_in[12];
  const float* bv = (const float*)d_in[13];
  const float* We = (const float*)d_in[14];
  const float* be = (const float*)d_in[15];
  const float* Wskip = (const float*)d_in[16];
  const float* bskip = (const float*)d_in[17];
  const float* W_down = (const float*)d_in[18];
  const float* b_down = (const float*)d_in[19];
  const float* W_out  = (const float*)d_in[20];
  const float* b_out  = (const float*)d_in[21];
  float* out = (float*)d_out;

  // workspace carve (~341 KB)
  float* p = (float*)d_ws;
  float* Gbuf  = p; p += 8192;
  float* bbuf  = p; p += 1024;
  float* bcatT = p; p += 16 * WC2;                 // 2304 floats
  unsigned short* WcatT = (unsigned short*)p;      // 16*144*64 bf16 = 294912 B (16B-aligned)

  k_prep2<<<36, 256, 0, stream>>>(We, be, W_edge, b_edge, Gbuf, bbuf);
  k_prepW<<<(16 * WC2 * 64) / 256, 256, 0, stream>>>(Wq, bq, Wk, bk, Wv, bv, Gbuf, bbuf,
                                                     WcatT, bcatT);
  k_fused<<<256, 1024, 0, stream>>>(x, W_node, b_node, WcatT, bcatT, edge_attr, ei,
                                    Gbuf, bbuf, Wskip, bskip, W_down, b_down, W_out, b_out,
                                    out);
}

// Round 2
// 707.724 us; speedup vs baseline: 1.0527x; 1.0527x over previous
//
#include <hip/hip_runtime.h>
#include <hip/hip_bf16.h>

constexpr int Ej  = 294912;  // total edges
constexpr int EPG = 1152;    // edges per graph
constexpr int WC2 = 144;     // fused-GEMM cols per head: A64 | V64 | r8:8 | cD | cS | pad6

typedef __attribute__((ext_vector_type(8))) short short8;   // 8 bf16 (MFMA A/B frag)
typedef __attribute__((ext_vector_type(4))) float f32x4;    // MFMA C/D frag

// monotone float<->uint encoding for atomicMax on floats
__device__ __forceinline__ unsigned encf(float f) {
  unsigned u = __float_as_uint(f);
  return (u & 0x80000000u) ? ~u : (u | 0x80000000u);
}
__device__ __forceinline__ float decf(unsigned u) {
  return (u & 0x80000000u) ? __uint_as_float(u & 0x7FFFFFFFu) : __uint_as_float(~u);
}
// fp32 -> bf16 bits, round-to-nearest-even
__device__ __forceinline__ unsigned short f2bf(float f) {
  unsigned u = __float_as_uint(f);
  u += 0x7FFFu + ((u >> 16) & 1u);
  return (unsigned short)(u >> 16);
}
// 64-lane sum via DPP. Result valid in lane 63.
__device__ __forceinline__ float wave_red_sum(float x) {
  x += __int_as_float(__builtin_amdgcn_update_dpp(0, __float_as_int(x), 0x111, 0xf, 0xf, true));
  x += __int_as_float(__builtin_amdgcn_update_dpp(0, __float_as_int(x), 0x112, 0xf, 0xf, true));
  x += __int_as_float(__builtin_amdgcn_update_dpp(0, __float_as_int(x), 0x114, 0xf, 0xf, true));
  x += __int_as_float(__builtin_amdgcn_update_dpp(0, __float_as_int(x), 0x118, 0xf, 0xf, true));
  x += __int_as_float(__builtin_amdgcn_update_dpp(0, __float_as_int(x), 0x142, 0xf, 0xf, true));
  x += __int_as_float(__builtin_amdgcn_update_dpp(0, __float_as_int(x), 0x143, 0xf, 0xf, true));
  return x;
}

// G[l][h][a][c] = sum_d W_edge[a,d]*We_l[d][h64+c];  bb[l][h][c] = be + b_edge@We
__global__ void k_prep2(const float* __restrict__ We, const float* __restrict__ be,
                        const float* __restrict__ W_edge, const float* __restrict__ b_edge,
                        float* __restrict__ G, float* __restrict__ bb) {
  int tid = blockIdx.x * 256 + threadIdx.x;  // 8192 + 1024
  if (tid < 8192) {
    int l = tid >> 11, rem = tid & 2047;
    int hh = rem >> 9, a = (rem >> 6) & 7, c = rem & 63;
    float acc = 0.f;
#pragma unroll 8
    for (int d = 0; d < 64; ++d)
      acc += W_edge[a * 64 + d] * We[l * 16384 + d * 256 + hh * 64 + c];
    G[tid] = acc;
  } else if (tid < 9216) {
    int t = tid - 8192;
    int l = t >> 8, rem = t & 255;
    int hh = rem >> 6, c = rem & 63;
    float acc = be[l * 256 + hh * 64 + c];
#pragma unroll 8
    for (int d = 0; d < 64; ++d)
      acc += b_edge[d] * We[l * 16384 + d * 256 + hh * 64 + c];
    bb[t] = acc;
  }
}

// WcatT [lh][col][kk] bf16 + bcatT fp32.
// col<64:   A  = 0.125*(Wq_h @ Wk_h^T)[kk][col], bias 0                 (scores via A@hB^T)
// col<128:  V  = Wv, bias bv
// col<136:  r8 = 0.125*Wq_h@G[a]^T, bias 0.125*bq_h.G[a]
// col==136: cD = 0.125*Wq_h@(bk+bb)^T, bias 0.125*bq.(bk+bb)   (per-dst scalar)
// col==137: cS = 0.125*Wk_h@bq^T, bias 0                        (per-src scalar)
__global__ void __launch_bounds__(256) k_prepW(
    const float* __restrict__ Wq, const float* __restrict__ bq,
    const float* __restrict__ Wk, const float* __restrict__ bk,
    const float* __restrict__ Wv, const float* __restrict__ bv,
    const float* __restrict__ Gbuf, const float* __restrict__ bbuf,
    unsigned short* __restrict__ WcatT, float* __restrict__ bcatT) {
  int t = blockIdx.x * 256 + threadIdx.x;  // 16*144*64
  if (t >= 16 * WC2 * 64) return;
  int kk = t & 63;
  int col = (t >> 6) % WC2;
  int lh = t / (WC2 * 64);
  int h = lh & 3, l = lh >> 2;
  const float* Wq_l = Wq + l * 16384;
  const float* Wk_l = Wk + l * 16384;
  const float* bq_l = bq + l * 256;
  const float* bk_l = bk + l * 256;
  float w = 0.f, bias = 0.f;
  if (col < 64) {
    float s = 0.f;
#pragma unroll 8
    for (int i = 0; i < 64; ++i)
      s += Wq_l[kk * 256 + h * 64 + i] * Wk_l[col * 256 + h * 64 + i];
    w = 0.125f * s;
  } else if (col < 128) {
    int j = col - 64;
    w = Wv[l * 16384 + kk * 256 + h * 64 + j];
    bias = bv[l * 256 + h * 64 + j];
  } else if (col < 136) {
    int a = col - 128;
    const float* Grow = Gbuf + l * 2048 + h * 512 + a * 64;
    float s = 0.f, sb = 0.f;
#pragma unroll 8
    for (int i = 0; i < 64; ++i) {
      s  += Wq_l[kk * 256 + h * 64 + i] * Grow[i];
      sb += bq_l[h * 64 + i] * Grow[i];
    }
    w = 0.125f * s; bias = 0.125f * sb;
  } else if (col == 136) {
    float s = 0.f, sb = 0.f;
#pragma unroll 8
    for (int i = 0; i < 64; ++i) {
      float bkb = bk_l[h * 64 + i] + bbuf[l * 256 + h * 64 + i];
      s  += Wq_l[kk * 256 + h * 64 + i] * bkb;
      sb += bq_l[h * 64 + i] * bkb;
    }
    w = 0.125f * s; bias = 0.125f * sb;
  } else if (col == 137) {
    float s = 0.f;
#pragma unroll 8
    for (int i = 0; i < 64; ++i)
      s += Wk_l[kk * 256 + h * 64 + i] * bq_l[h * 64 + i];
    w = 0.125f * s;
  }
  WcatT[(size_t)(lh * WC2 + col) * 64 + kk] = f2bf(w);
  if (kk == 0) bcatT[lh * WC2 + col] = bias;
}

// One block per graph: node_enc + 4 layers x (4 heads x attention) x fused update + head.
// h resident in LDS fp32 (stride 68). agg accumulated across heads in MFMA C registers.
// Per-edge state (src/dst, ea[8], alpha) in registers across P2..P4.
// ALL per-thread arrays statically indexed (rule #20): wave wv owns m-strip (wv&7)*16 and
// n-tiles j0+{0,32,64,96[,128 if wv<8]}, j0=(wv&8)?16:0 -> V tiles are ALWAYS j==2,3.
// LDS total 155136 B -> 1 block/CU, 16 waves.
__global__ void __launch_bounds__(1024, 4) k_fused(
    const float* __restrict__ x, const float* __restrict__ W_node, const float* __restrict__ b_node,
    const unsigned short* __restrict__ WcatT, const float* __restrict__ bcatT,
    const float* __restrict__ edge_attr, const int* __restrict__ ei,
    const float* __restrict__ Gbuf, const float* __restrict__ bbuf,
    const float* __restrict__ Wskip, const float* __restrict__ bskip,
    const float* __restrict__ Wd, const float* __restrict__ bd,
    const float* __restrict__ Wo, const float* __restrict__ bo,
    float* __restrict__ out) {
  __shared__ float SS[16384];              // 65536 B: WT stage | scores (swizzled) | Wmat bf16 | Wskip
  __shared__ float h32[128 * 68];          // 34816 B: resident fp32 h
  __shared__ unsigned short hB[128 * 80];  // 20480 B: bf16 h (per-layer)
  __shared__ unsigned short AV[128 * 80];  // 20480 B: A-matrix (P0-P1), then Vt bf16 64x136 (P2-P5)
  __shared__ float r8L[128 * 8];           // 4096
  __shared__ float t8L[128 * 9];           // 4608
  __shared__ unsigned mL[128];             // 512
  __shared__ float sL[128];                // 512
  __shared__ float cDL[128];               // 512
  __shared__ float cSL[128];               // 512
  __shared__ float GhL[512];               // 2048
  __shared__ float vembL[256];             // 1024

  int g = blockIdx.x, tid = threadIdx.x;
  int lane = tid & 63, m16 = lane & 15, quad = lane >> 4, wv = tid >> 6;

  // prefetch WT for (l=0,h=0) into regs (consumed at first stage)
  uint4 wpA = ((const uint4*)WcatT)[tid];
  uint4 wpB;
  if (tid < 128) wpB = ((const uint4*)WcatT)[1024 + tid];

  // node encoder -> h32
  for (int idx = tid; idx < 8192; idx += 1024) {
    int n = idx >> 6, c = idx & 63;
    const float* xr = x + (size_t)(g * 128 + n) * 16;
    float acc = b_node[c];
#pragma unroll
    for (int d = 0; d < 16; ++d) acc += xr[d] * W_node[d * 64 + c];
    h32[n * 68 + c] = acc;
  }

  // per-edge registers: edge A = tid, edge B = 1024+tid (tid<128)
  const float* eaG = edge_attr + (size_t)g * EPG * 8;
  int edA, edB = 0;
  float4 eaA0, eaA1;
  float4 eaB0 = make_float4(0, 0, 0, 0), eaB1 = make_float4(0, 0, 0, 0);
  {
    int s = ei[g * EPG + tid] - g * 128;
    int d = ei[Ej + g * EPG + tid] - g * 128;
    edA = s | (d << 8);
    eaA0 = *(const float4*)(eaG + (size_t)tid * 8);
    eaA1 = *(const float4*)(eaG + (size_t)tid * 8 + 4);
  }
  bool hasB = tid < (EPG - 1024);
  if (hasB) {
    int e = 1024 + tid;
    int s = ei[g * EPG + e] - g * 128;
    int d = ei[Ej + g * EPG + e] - g * 128;
    edB = s | (d << 8);
    eaB0 = *(const float4*)(eaG + (size_t)e * 8);
    eaB1 = *(const float4*)(eaG + (size_t)e * 8 + 4);
  }
  __syncthreads();

  // static per-wave P0/P2 geometry
  const int m0 = (wv & 7) * 16;          // m-strip (rows of hB / output nodes)
  const int j0 = (wv & 8) ? 16 : 0;      // n-tile base offset
  const int vcA = j0;                    // V-col base of j==2 tile (n0-64)
  const bool lowHalf = (wv & 8) == 0;    // handles n0=128 tile

  for (int l = 0; l < 4; ++l) {
    // stage hB = bf16(h32)
    {
      int n8 = tid >> 3, c8 = tid & 7;
      const float* hr = &h32[n8 * 68 + c8 * 8];
      float4 a0 = *(const float4*)hr, a1 = *(const float4*)(hr + 4);
      uint4 hp;
      hp.x = f2bf(a0.x) | ((unsigned)f2bf(a0.y) << 16);
      hp.y = f2bf(a0.z) | ((unsigned)f2bf(a0.w) << 16);
      hp.z = f2bf(a1.x) | ((unsigned)f2bf(a1.y) << 16);
      hp.w = f2bf(a1.z) | ((unsigned)f2bf(a1.w) << 16);
      *(uint4*)&hB[n8 * 80 + c8 * 8] = hp;
    }
    f32x4 accP5_0 = {0.f, 0.f, 0.f, 0.f};
    f32x4 accP5_1 = {0.f, 0.f, 0.f, 0.f};
    float4 wskpre;

    for (int h = 0; h < 4; ++h) {
      __syncthreads();  // prev head's P5 / layer-top hB stage complete
      // ---- stage: WT (from prefetch regs) into SS, GhL, zero mL/sL/t8L
      {
        unsigned short* WT = (unsigned short*)SS;
        ((uint4*)WT)[tid] = wpA;
        if (tid < 128) ((uint4*)WT)[1024 + tid] = wpB;
      }
      for (int idx = tid; idx < 512; idx += 1024) GhL[idx] = Gbuf[l * 2048 + h * 512 + idx];
      if (tid < 128) { mL[tid] = 0u; sL[tid] = 0.f; }
      for (int idx = tid; idx < 1152; idx += 1024) t8L[idx] = 0.f;
      __syncthreads();

      // ---- P0: fused GEMM out[node][col] = hB @ WT^T + bias (static tile->wave map)
      const unsigned short* WT = (const unsigned short*)SS;
      const float* bcTl = bcatT + (l * 4 + h) * WC2;
      f32x4 vfragA, vfragB;
      {
        const short8 a0 = *(const short8*)&hB[(m0 + m16) * 80 + quad * 8];
        const short8 a1 = *(const short8*)&hB[(m0 + m16) * 80 + 32 + quad * 8];
#pragma unroll
        for (int j = 0; j < 4; ++j) {
          int n0 = j0 + j * 32;
          const short8 b0 = *(const short8*)&WT[(n0 + m16) * 64 + quad * 8];
          const short8 b1 = *(const short8*)&WT[(n0 + m16) * 64 + 32 + quad * 8];
          float bias = bcTl[n0 + m16];
          f32x4 acc = {bias, bias, bias, bias};
          acc = __builtin_amdgcn_mfma_f32_16x16x32_bf16(a0, b0, acc, 0, 0, 0);
          acc = __builtin_amdgcn_mfma_f32_16x16x32_bf16(a1, b1, acc, 0, 0, 0);
          if (j == 0 || j == 1) {
#pragma unroll
            for (int r = 0; r < 4; ++r)
              AV[(m0 + quad * 4 + r) * 80 + n0 + m16] = f2bf(acc[r]);
          } else if (j == 2) {
            vfragA = acc;
          } else {
            vfragB = acc;
          }
        }
        if (lowHalf) {  // n0 = 128 tile: r8 | cD | cS
          const short8 b0 = *(const short8*)&WT[(128 + m16) * 64 + quad * 8];
          const short8 b1 = *(const short8*)&WT[(128 + m16) * 64 + 32 + quad * 8];
          float bias = bcTl[128 + m16];
          f32x4 acc = {bias, bias, bias, bias};
          acc = __builtin_amdgcn_mfma_f32_16x16x32_bf16(a0, b0, acc, 0, 0, 0);
          acc = __builtin_amdgcn_mfma_f32_16x16x32_bf16(a1, b1, acc, 0, 0, 0);
          if (m16 < 8) {
#pragma unroll
            for (int r = 0; r < 4; ++r) r8L[(m0 + quad * 4 + r) * 8 + m16] = acc[r];
          } else if (m16 == 8) {
#pragma unroll
            for (int r = 0; r < 4; ++r) cDL[m0 + quad * 4 + r] = acc[r];
          } else if (m16 == 9) {
#pragma unroll
            for (int r = 0; r < 4; ++r) cSL[m0 + quad * 4 + r] = acc[r];
          }
        }
      }
      __syncthreads();

      // ---- P1: scores = A @ hB^T -> SS fp32, col XOR-swizzled per row
      {
        int strip = wv >> 1, halfw = wv & 1, dst0 = strip * 16;
        const short8 a0 = *(const short8*)&AV[(dst0 + m16) * 80 + quad * 8];
        const short8 a1 = *(const short8*)&AV[(dst0 + m16) * 80 + 32 + quad * 8];
#pragma unroll
        for (int t = 0; t < 4; ++t) {
          int src0 = (halfw * 4 + t) * 16;
          const short8 b0 = *(const short8*)&hB[(src0 + m16) * 80 + quad * 8];
          const short8 b1 = *(const short8*)&hB[(src0 + m16) * 80 + 32 + quad * 8];
          f32x4 acc = {0.f, 0.f, 0.f, 0.f};
          acc = __builtin_amdgcn_mfma_f32_16x16x32_bf16(a0, b0, acc, 0, 0, 0);
          acc = __builtin_amdgcn_mfma_f32_16x16x32_bf16(a1, b1, acc, 0, 0, 0);
#pragma unroll
          for (int r = 0; r < 4; ++r) {
            int row = dst0 + quad * 4 + r;
            SS[row * 128 + ((src0 + m16) ^ ((row & 7) << 4))] = acc[r];
          }
        }
      }
      __syncthreads();

      // ---- P2: deposit v frags -> Vt (AV region, bf16, transposed); alpha + segment max
#pragma unroll
      for (int r = 0; r < 4; ++r)
        AV[(vcA + m16) * 136 + m0 + quad * 4 + r] = f2bf(vfragA[r]);
#pragma unroll
      for (int r = 0; r < 4; ++r)
        AV[(vcA + 32 + m16) * 136 + m0 + quad * 4 + r] = f2bf(vfragB[r]);
      float aA, aB = 0.f;
      {
        int src = edA & 255, dst = edA >> 8;
        float4 r80 = *(const float4*)&r8L[dst * 8];
        float4 r81 = *(const float4*)&r8L[dst * 8 + 4];
        aA = SS[dst * 128 + (src ^ ((dst & 7) << 4))] + cDL[dst] + cSL[src]
           + eaA0.x * r80.x + eaA0.y * r80.y + eaA0.z * r80.z + eaA0.w * r80.w
           + eaA1.x * r81.x + eaA1.y * r81.y + eaA1.z * r81.z + eaA1.w * r81.w;
        atomicMax(&mL[dst], encf(aA));
      }
      if (hasB) {
        int src = edB & 255, dst = edB >> 8;
        float4 r80 = *(const float4*)&r8L[dst * 8];
        float4 r81 = *(const float4*)&r8L[dst * 8 + 4];
        aB = SS[dst * 128 + (src ^ ((dst & 7) << 4))] + cDL[dst] + cSL[src]
           + eaB0.x * r80.x + eaB0.y * r80.y + eaB0.z * r80.z + eaB0.w * r80.w
           + eaB1.x * r81.x + eaB1.y * r81.y + eaB1.z * r81.z + eaB1.w * r81.w;
        atomicMax(&mL[dst], encf(aB));
      }
      __syncthreads();

      // ---- P3: zero SS; exp + segment sum (alpha stays in regs)
      for (int idx = tid; idx < 4096; idx += 1024)
        *(float4*)&SS[idx * 4] = make_float4(0.f, 0.f, 0.f, 0.f);
      {
        int dst = edA >> 8;
        aA = expf(aA - decf(mL[dst]));
        atomicAdd(&sL[dst], aA);
      }
      if (hasB) {
        int dst = edB >> 8;
        aB = expf(aB - decf(mL[dst]));
        atomicAdd(&sL[dst], aB);
      }
      __syncthreads();

      // ---- P4: scatter normalized weights into Wmat(fp32, swizzled); accumulate t8
      {
        int src = edA & 255, dst = edA >> 8;
        float w = aA / fmaxf(sL[dst], 1e-16f);
        atomicAdd(&SS[dst * 128 + (src ^ ((dst & 7) << 4))], w);
        float* t8 = &t8L[dst * 9];
        atomicAdd(t8 + 0, w * eaA0.x); atomicAdd(t8 + 1, w * eaA0.y);
        atomicAdd(t8 + 2, w * eaA0.z); atomicAdd(t8 + 3, w * eaA0.w);
        atomicAdd(t8 + 4, w * eaA1.x); atomicAdd(t8 + 5, w * eaA1.y);
        atomicAdd(t8 + 6, w * eaA1.z); atomicAdd(t8 + 7, w * eaA1.w);
      }
      if (hasB) {
        int src = edB & 255, dst = edB >> 8;
        float w = aB / fmaxf(sL[dst], 1e-16f);
        atomicAdd(&SS[dst * 128 + (src ^ ((dst & 7) << 4))], w);
        float* t8 = &t8L[dst * 9];
        atomicAdd(t8 + 0, w * eaB0.x); atomicAdd(t8 + 1, w * eaB0.y);
        atomicAdd(t8 + 2, w * eaB0.z); atomicAdd(t8 + 3, w * eaB0.w);
        atomicAdd(t8 + 4, w * eaB1.x); atomicAdd(t8 + 5, w * eaB1.y);
        atomicAdd(t8 + 6, w * eaB1.z); atomicAdd(t8 + 7, w * eaB1.w);
      }
      __syncthreads();

      // ---- P4.5: repack Wmat fp32(swizzled) -> bf16 stride 136 in place
      {
        float vals[16];
        int i0 = tid * 16;
        int dst = i0 >> 7, src0 = i0 & 127;
        int base = dst * 128 + (src0 ^ ((dst & 7) << 4));
#pragma unroll
        for (int i = 0; i < 16; ++i) vals[i] = SS[base + i];
        __syncthreads();
        unsigned short* Wu = (unsigned short*)SS;
#pragma unroll
        for (int g4 = 0; g4 < 2; ++g4) {
          uint4 u;
          u.x = f2bf(vals[g4 * 8 + 0]) | ((unsigned)f2bf(vals[g4 * 8 + 1]) << 16);
          u.y = f2bf(vals[g4 * 8 + 2]) | ((unsigned)f2bf(vals[g4 * 8 + 3]) << 16);
          u.z = f2bf(vals[g4 * 8 + 4]) | ((unsigned)f2bf(vals[g4 * 8 + 5]) << 16);
          u.w = f2bf(vals[g4 * 8 + 6]) | ((unsigned)f2bf(vals[g4 * 8 + 7]) << 16);
          *(uint4*)&Wu[dst * 136 + src0 + g4 * 8] = u;
        }
      }
      __syncthreads();

      // ---- P5: accP5 += Wmat@Vt (MFMA) + t8@G + sw*bb ; prefetch next WT / Wskip
      {
        int nlh = l * 4 + h + 1;
        if (nlh < 16) {
          const uint4* wsrc = (const uint4*)(WcatT + (size_t)nlh * (WC2 * 64));
          wpA = wsrc[tid];
          if (tid < 128) wpB = wsrc[1024 + tid];
        }
        if (h == 3) wskpre = ((const float4*)(Wskip + (size_t)l * 4096))[tid];

        const unsigned short* Wu = (const unsigned short*)SS;
        int strip = wv >> 1, halfc = wv & 1, dst0 = strip * 16;
        short8 a[4];
#pragma unroll
        for (int ks = 0; ks < 4; ++ks)
          a[ks] = *(const short8*)&Wu[(dst0 + m16) * 136 + ks * 32 + quad * 8];
#pragma unroll
        for (int t2 = 0; t2 < 2; ++t2) {
          int c0 = (halfc * 2 + t2) * 16;
          f32x4 acc = (t2 == 0) ? accP5_0 : accP5_1;
#pragma unroll
          for (int ks = 0; ks < 4; ++ks) {
            const short8 b = *(const short8*)&AV[(c0 + m16) * 136 + ks * 32 + quad * 8];
            acc = __builtin_amdgcn_mfma_f32_16x16x32_bf16(a[ks], b, acc, 0, 0, 0);
          }
          int col = c0 + m16;
          float bbv = bbuf[l * 256 + h * 64 + col];
          float gcol[8];
#pragma unroll
          for (int a8 = 0; a8 < 8; ++a8) gcol[a8] = GhL[a8 * 64 + col];
#pragma unroll
          for (int r = 0; r < 4; ++r) {
            int row = dst0 + quad * 4 + r;
            float add = (sL[row] > 0.f) ? bbv : 0.f;
#pragma unroll
            for (int a8 = 0; a8 < 8; ++a8) add += t8L[row * 9 + a8] * gcol[a8];
            acc[r] += add;
          }
          if (t2 == 0) accP5_0 = acc; else accP5_1 = acc;
        }
      }
    }  // heads

    // ---- update: out = 0.25*acc + h@Wskip+bskip ; vemb ; h += out (all in LDS)
    __syncthreads();
    *(float4*)&SS[tid * 4] = wskpre;  // Wskip_l staged to SS[0..4096)
    __syncthreads();
    {
      int strip = wv >> 1, halfc = wv & 1, dst0 = strip * 16;
      float sk0[4], sk1[4];
#pragma unroll
      for (int t2 = 0; t2 < 2; ++t2) {
        int col = halfc * 32 + t2 * 16 + m16;
        float bsv = bskip[l * 64 + col];
#pragma unroll
        for (int r = 0; r < 4; ++r) {
          int row = dst0 + quad * 4 + r;
          float s = bsv;
#pragma unroll 8
          for (int d = 0; d < 64; ++d) s += h32[row * 68 + d] * SS[d * 64 + col];
          if (t2 == 0) sk0[r] = s; else sk1[r] = s;
        }
      }
      __syncthreads();  // all h32 reads done before in-place writes
#pragma unroll
      for (int t2 = 0; t2 < 2; ++t2) {
        int col = halfc * 32 + t2 * 16 + m16;
#pragma unroll
        for (int r = 0; r < 4; ++r) {
          int row = dst0 + quad * 4 + r;
          float outv = ((t2 == 0) ? accP5_0[r] : accP5_1[r]) * 0.25f +
                       ((t2 == 0) ? sk0[r] : sk1[r]);
          float hnew = outv + h32[row * 68 + col];
          h32[row * 68 + col] = hnew;
          if (row == 127) vembL[l * 64 + col] = outv;
        }
      }
    }
    __syncthreads();
  }  // layers

  // ---- head: pool = vemb @ W_down + b_down; out = sigmoid(pool @ W_out + b_out)
  {
    float part = 0.f;
#pragma unroll
    for (int j2 = 0; j2 < 16; ++j2) {
      int j = wv * 16 + j2;
      part += vembL[j] * Wd[j * 64 + lane];
    }
    SS[wv * 64 + lane] = part;
    __syncthreads();
    if (wv == 0) {
      float acc = bd[lane];
#pragma unroll
      for (int w2 = 0; w2 < 16; ++w2) acc += SS[w2 * 64 + lane];
      float p = acc * Wo[lane];
      p = wave_red_sum(p);
      if (lane == 63) out[g] = 1.f / (1.f + expf(-(p + bo[0])));
    }
  }
}

extern "C" void kernel_launch(void* const* d_in, const int* in_sizes, int n_in,
                              void* d_out, int out_size, void* d_ws, size_t ws_size,
                              hipStream_t stream) {
  const float* x         = (const float*)d_in[0];
  const float* edge_attr = (const float*)d_in[1];
  const int*   ei        = (const int*)d_in[2];
  const float* W_node = (const float*)d_in[4];
  const float* b_node = (const float*)d_in[5];
  const float* W_edge = (const float*)d_in[6];
  const float* b_edge = (const float*)d_in[7];
  const float* Wq = (const float*)d_in[8];
  const float* bq = (const float*)d_in[9];
  const float* Wk = (const float*)d_in[10];
  const float* bk = (const float*)d_in[11];
  const float* Wv = (const float*)d_in[12];
  const float* bv = (const float*)d_in[13];
  const float* We = (const float*)d_in[14];
  const float* be = (const float*)d_in[15];
  const float* Wskip = (const float*)d_in[16];
  const float* bskip = (const float*)d_in[17];
  const float* W_down = (const float*)d_in[18];
  const float* b_down = (const float*)d_in[19];
  const float* W_out  = (const float*)d_in[20];
  const float* b_out  = (const float*)d_in[21];
  float* out = (float*)d_out;

  // workspace carve (~341 KB)
  float* p = (float*)d_ws;
  float* Gbuf  = p; p += 8192;
  float* bbuf  = p; p += 1024;
  float* bcatT = p; p += 16 * WC2;                 // 2304 floats
  unsigned short* WcatT = (unsigned short*)p;      // 16*144*64 bf16 = 294912 B (16B-aligned)

  k_prep2<<<36, 256, 0, stream>>>(We, be, W_edge, b_edge, Gbuf, bbuf);
  k_prepW<<<(16 * WC2 * 64) / 256, 256, 0, stream>>>(Wq, bq, Wk, bk, Wv, bv, Gbuf, bbuf,
                                                     WcatT, bcatT);
  k_fused<<<256, 1024, 0, stream>>>(x, W_node, b_node, WcatT, bcatT, edge_attr, ei,
                                    Gbuf, bbuf, Wskip, bskip, W_down, b_down, W_out, b_out,
                                    out);
}

// Round 3
// 507.610 us; speedup vs baseline: 1.4677x; 1.3942x over previous
//
#include <hip/hip_runtime.h>
#include <hip/hip_bf16.h>

constexpr int Ej  = 294912;  // total edges
constexpr int EPG = 1152;    // edges per graph
constexpr int WC2 = 144;     // fused-GEMM cols per head: A64 | V64 | r8:8 | cD | cS | pad6

typedef __attribute__((ext_vector_type(8))) short short8;   // 8 bf16 (MFMA A/B frag)
typedef __attribute__((ext_vector_type(4))) float f32x4;    // MFMA C/D frag

// monotone float<->uint encoding for atomicMax on floats
__device__ __forceinline__ unsigned encf(float f) {
  unsigned u = __float_as_uint(f);
  return (u & 0x80000000u) ? ~u : (u | 0x80000000u);
}
__device__ __forceinline__ float decf(unsigned u) {
  return (u & 0x80000000u) ? __uint_as_float(u & 0x7FFFFFFFu) : __uint_as_float(~u);
}
// fp32 -> bf16 bits, round-to-nearest-even
__device__ __forceinline__ unsigned short f2bf(float f) {
  unsigned u = __float_as_uint(f);
  u += 0x7FFFu + ((u >> 16) & 1u);
  return (unsigned short)(u >> 16);
}
// 64-lane sum via DPP. Result valid in lane 63.
__device__ __forceinline__ float wave_red_sum(float x) {
  x += __int_as_float(__builtin_amdgcn_update_dpp(0, __float_as_int(x), 0x111, 0xf, 0xf, true));
  x += __int_as_float(__builtin_amdgcn_update_dpp(0, __float_as_int(x), 0x112, 0xf, 0xf, true));
  x += __int_as_float(__builtin_amdgcn_update_dpp(0, __float_as_int(x), 0x114, 0xf, 0xf, true));
  x += __int_as_float(__builtin_amdgcn_update_dpp(0, __float_as_int(x), 0x118, 0xf, 0xf, true));
  x += __int_as_float(__builtin_amdgcn_update_dpp(0, __float_as_int(x), 0x142, 0xf, 0xf, true));
  x += __int_as_float(__builtin_amdgcn_update_dpp(0, __float_as_int(x), 0x143, 0xf, 0xf, true));
  return x;
}

// G[l][h][a][c] = sum_d W_edge[a,d]*We_l[d][h64+c];  bb[l][h][c] = be + b_edge@We
__global__ void k_prep2(const float* __restrict__ We, const float* __restrict__ be,
                        const float* __restrict__ W_edge, const float* __restrict__ b_edge,
                        float* __restrict__ G, float* __restrict__ bb) {
  int tid = blockIdx.x * 256 + threadIdx.x;  // 8192 + 1024
  if (tid < 8192) {
    int l = tid >> 11, rem = tid & 2047;
    int hh = rem >> 9, a = (rem >> 6) & 7, c = rem & 63;
    float acc = 0.f;
#pragma unroll 8
    for (int d = 0; d < 64; ++d)
      acc += W_edge[a * 64 + d] * We[l * 16384 + d * 256 + hh * 64 + c];
    G[tid] = acc;
  } else if (tid < 9216) {
    int t = tid - 8192;
    int l = t >> 8, rem = t & 255;
    int hh = rem >> 6, c = rem & 63;
    float acc = be[l * 256 + hh * 64 + c];
#pragma unroll 8
    for (int d = 0; d < 64; ++d)
      acc += b_edge[d] * We[l * 16384 + d * 256 + hh * 64 + c];
    bb[t] = acc;
  }
}

// WcatT [lh][col][kk] bf16 + bcatT fp32.
// col<64:   A  = 0.125*(Wq_h @ Wk_h^T)[kk][col], bias 0                 (scores via A@hB^T)
// col<128:  V  = Wv, bias bv
// col<136:  r8 = 0.125*Wq_h@G[a]^T, bias 0.125*bq_h.G[a]
// col==136: cD = 0.125*Wq_h@(bk+bb)^T, bias 0.125*bq.(bk+bb)   (per-dst scalar)
// col==137: cS = 0.125*Wk_h@bq^T, bias 0                        (per-src scalar)
__global__ void __launch_bounds__(256) k_prepW(
    const float* __restrict__ Wq, const float* __restrict__ bq,
    const float* __restrict__ Wk, const float* __restrict__ bk,
    const float* __restrict__ Wv, const float* __restrict__ bv,
    const float* __restrict__ Gbuf, const float* __restrict__ bbuf,
    unsigned short* __restrict__ WcatT, float* __restrict__ bcatT) {
  int t = blockIdx.x * 256 + threadIdx.x;  // 16*144*64
  if (t >= 16 * WC2 * 64) return;
  int kk = t & 63;
  int col = (t >> 6) % WC2;
  int lh = t / (WC2 * 64);
  int h = lh & 3, l = lh >> 2;
  const float* Wq_l = Wq + l * 16384;
  const float* Wk_l = Wk + l * 16384;
  const float* bq_l = bq + l * 256;
  const float* bk_l = bk + l * 256;
  float w = 0.f, bias = 0.f;
  if (col < 64) {
    float s = 0.f;
#pragma unroll 8
    for (int i = 0; i < 64; ++i)
      s += Wq_l[kk * 256 + h * 64 + i] * Wk_l[col * 256 + h * 64 + i];
    w = 0.125f * s;
  } else if (col < 128) {
    int j = col - 64;
    w = Wv[l * 16384 + kk * 256 + h * 64 + j];
    bias = bv[l * 256 + h * 64 + j];
  } else if (col < 136) {
    int a = col - 128;
    const float* Grow = Gbuf + l * 2048 + h * 512 + a * 64;
    float s = 0.f, sb = 0.f;
#pragma unroll 8
    for (int i = 0; i < 64; ++i) {
      s  += Wq_l[kk * 256 + h * 64 + i] * Grow[i];
      sb += bq_l[h * 64 + i] * Grow[i];
    }
    w = 0.125f * s; bias = 0.125f * sb;
  } else if (col == 136) {
    float s = 0.f, sb = 0.f;
#pragma unroll 8
    for (int i = 0; i < 64; ++i) {
      float bkb = bk_l[h * 64 + i] + bbuf[l * 256 + h * 64 + i];
      s  += Wq_l[kk * 256 + h * 64 + i] * bkb;
      sb += bq_l[h * 64 + i] * bkb;
    }
    w = 0.125f * s; bias = 0.125f * sb;
  } else if (col == 137) {
    float s = 0.f;
#pragma unroll 8
    for (int i = 0; i < 64; ++i)
      s += Wk_l[kk * 256 + h * 64 + i] * bq_l[h * 64 + i];
    w = 0.125f * s;
  }
  WcatT[(size_t)(lh * WC2 + col) * 64 + kk] = f2bf(w);
  if (kk == 0) bcatT[lh * WC2 + col] = bias;
}

// One block per graph, 512 threads (8 waves): node_enc + 4 layers x 4 heads + head readout.
// 512 threads => 2 waves/SIMD resident => 256-reg/wave budget (vs 128 at 1024 thr) => no spill.
// Wave wv owns m-strip wv*16 everywhere. All per-thread arrays statically indexed.
// LDS total 155136 B -> 1 block/CU.
__global__ void __launch_bounds__(512, 2) k_fused(
    const float* __restrict__ x, const float* __restrict__ W_node, const float* __restrict__ b_node,
    const unsigned short* __restrict__ WcatT, const float* __restrict__ bcatT,
    const float* __restrict__ edge_attr, const int* __restrict__ ei,
    const float* __restrict__ Gbuf, const float* __restrict__ bbuf,
    const float* __restrict__ Wskip, const float* __restrict__ bskip,
    const float* __restrict__ Wd, const float* __restrict__ bd,
    const float* __restrict__ Wo, const float* __restrict__ bo,
    float* __restrict__ out) {
  __shared__ float SS[16384];              // 65536 B: WT stage | scores (swizzled) | Wmat bf16 | Wskip
  __shared__ float h32[128 * 68];          // 34816 B: resident fp32 h
  __shared__ unsigned short hB[128 * 80];  // 20480 B: bf16 h (per-layer)
  __shared__ unsigned short AV[128 * 80];  // 20480 B: A-matrix (P0-P1), then Vt bf16 64x136 (P2-P5)
  __shared__ float r8L[128 * 8];           // 4096
  __shared__ float t8L[128 * 9];           // 4608
  __shared__ unsigned mL[128];             // 512
  __shared__ float sL[128];                // 512
  __shared__ float cDL[128];               // 512
  __shared__ float cSL[128];               // 512
  __shared__ float GhL[512];               // 2048
  __shared__ float vembL[256];             // 1024

  int g = blockIdx.x, tid = threadIdx.x;
  int lane = tid & 63, m16 = lane & 15, quad = lane >> 4, wv = tid >> 6;  // wv in 0..7

  // prefetch WT for (l=0,h=0) into regs: 1152 uint4 over 512 threads (2.25 each)
  uint4 wpA = ((const uint4*)WcatT)[tid];
  uint4 wpB = ((const uint4*)WcatT)[512 + tid];
  uint4 wpC;
  bool hasC = tid < 128;
  if (hasC) wpC = ((const uint4*)WcatT)[1024 + tid];

  // node encoder -> h32
  for (int idx = tid; idx < 8192; idx += 512) {
    int n = idx >> 6, c = idx & 63;
    const float* xr = x + (size_t)(g * 128 + n) * 16;
    float acc = b_node[c];
#pragma unroll
    for (int d = 0; d < 16; ++d) acc += xr[d] * W_node[d * 64 + c];
    h32[n * 68 + c] = acc;
  }

  // per-edge registers: A = tid, B = 512+tid, C = 1024+tid (tid<128)
  const float* eaG = edge_attr + (size_t)g * EPG * 8;
  int edA, edB, edC = 0;
  float4 eaA0, eaA1, eaB0, eaB1;
  float4 eaC0 = make_float4(0, 0, 0, 0), eaC1 = make_float4(0, 0, 0, 0);
  {
    int s = ei[g * EPG + tid] - g * 128;
    int d = ei[Ej + g * EPG + tid] - g * 128;
    edA = s | (d << 8);
    eaA0 = *(const float4*)(eaG + (size_t)tid * 8);
    eaA1 = *(const float4*)(eaG + (size_t)tid * 8 + 4);
  }
  {
    int e = 512 + tid;
    int s = ei[g * EPG + e] - g * 128;
    int d = ei[Ej + g * EPG + e] - g * 128;
    edB = s | (d << 8);
    eaB0 = *(const float4*)(eaG + (size_t)e * 8);
    eaB1 = *(const float4*)(eaG + (size_t)e * 8 + 4);
  }
  if (hasC) {
    int e = 1024 + tid;
    int s = ei[g * EPG + e] - g * 128;
    int d = ei[Ej + g * EPG + e] - g * 128;
    edC = s | (d << 8);
    eaC0 = *(const float4*)(eaG + (size_t)e * 8);
    eaC1 = *(const float4*)(eaG + (size_t)e * 8 + 4);
  }
  __syncthreads();

  const int m0 = wv * 16;  // this wave's m-strip / dst-strip everywhere

  for (int l = 0; l < 4; ++l) {
    // stage hB = bf16(h32): 2 slices of 64 rows
    {
      int n8 = tid >> 3, c8 = tid & 7;
#pragma unroll
      for (int s2 = 0; s2 < 2; ++s2) {
        int row = n8 + s2 * 64;
        const float* hr = &h32[row * 68 + c8 * 8];
        float4 a0 = *(const float4*)hr, a1 = *(const float4*)(hr + 4);
        uint4 hp;
        hp.x = f2bf(a0.x) | ((unsigned)f2bf(a0.y) << 16);
        hp.y = f2bf(a0.z) | ((unsigned)f2bf(a0.w) << 16);
        hp.z = f2bf(a1.x) | ((unsigned)f2bf(a1.y) << 16);
        hp.w = f2bf(a1.z) | ((unsigned)f2bf(a1.w) << 16);
        *(uint4*)&hB[row * 80 + c8 * 8] = hp;
      }
    }
    f32x4 accP5_0 = {0.f, 0.f, 0.f, 0.f};
    f32x4 accP5_1 = {0.f, 0.f, 0.f, 0.f};
    f32x4 accP5_2 = {0.f, 0.f, 0.f, 0.f};
    f32x4 accP5_3 = {0.f, 0.f, 0.f, 0.f};
    float4 wsk0, wsk1;

    for (int h = 0; h < 4; ++h) {
      __syncthreads();  // prev head's P5 / layer-top hB stage complete
      // ---- stage: WT (from prefetch regs) into SS, GhL, zero mL/sL/t8L
      {
        unsigned short* WT = (unsigned short*)SS;
        ((uint4*)WT)[tid] = wpA;
        ((uint4*)WT)[512 + tid] = wpB;
        if (hasC) ((uint4*)WT)[1024 + tid] = wpC;
      }
      GhL[tid] = Gbuf[l * 2048 + h * 512 + tid];
      if (tid < 128) { mL[tid] = 0u; sL[tid] = 0.f; }
      t8L[tid] = 0.f; t8L[512 + tid] = 0.f;
      if (hasC) t8L[1024 + tid] = 0.f;
      __syncthreads();

      // ---- P0: fused GEMM out[node][col] = hB @ WT^T + bias. Wave wv: m-strip m0, 9 n-tiles.
      const unsigned short* WT = (const unsigned short*)SS;
      const float* bcTl = bcatT + (l * 4 + h) * WC2;
      f32x4 vf0, vf1, vf2, vf3;
      {
        const short8 a0 = *(const short8*)&hB[(m0 + m16) * 80 + quad * 8];
        const short8 a1 = *(const short8*)&hB[(m0 + m16) * 80 + 32 + quad * 8];
#pragma unroll
        for (int nt = 0; nt < 9; ++nt) {
          int n0 = nt * 16;
          const short8 b0 = *(const short8*)&WT[(n0 + m16) * 64 + quad * 8];
          const short8 b1 = *(const short8*)&WT[(n0 + m16) * 64 + 32 + quad * 8];
          float bias = bcTl[n0 + m16];
          f32x4 acc = {bias, bias, bias, bias};
          acc = __builtin_amdgcn_mfma_f32_16x16x32_bf16(a0, b0, acc, 0, 0, 0);
          acc = __builtin_amdgcn_mfma_f32_16x16x32_bf16(a1, b1, acc, 0, 0, 0);
          if (nt < 4) {
#pragma unroll
            for (int r = 0; r < 4; ++r)
              AV[(m0 + quad * 4 + r) * 80 + n0 + m16] = f2bf(acc[r]);
          } else if (nt == 4) {
            vf0 = acc;
          } else if (nt == 5) {
            vf1 = acc;
          } else if (nt == 6) {
            vf2 = acc;
          } else if (nt == 7) {
            vf3 = acc;
          } else {  // nt == 8: r8 | cD | cS
            if (m16 < 8) {
#pragma unroll
              for (int r = 0; r < 4; ++r) r8L[(m0 + quad * 4 + r) * 8 + m16] = acc[r];
            } else if (m16 == 8) {
#pragma unroll
              for (int r = 0; r < 4; ++r) cDL[m0 + quad * 4 + r] = acc[r];
            } else if (m16 == 9) {
#pragma unroll
              for (int r = 0; r < 4; ++r) cSL[m0 + quad * 4 + r] = acc[r];
            }
          }
        }
      }
      __syncthreads();

      // ---- P1: scores = A @ hB^T -> SS fp32, col XOR-swizzled per row. Wave wv: 8 src tiles.
      {
        const short8 a0 = *(const short8*)&AV[(m0 + m16) * 80 + quad * 8];
        const short8 a1 = *(const short8*)&AV[(m0 + m16) * 80 + 32 + quad * 8];
#pragma unroll
        for (int t = 0; t < 8; ++t) {
          int src0 = t * 16;
          const short8 b0 = *(const short8*)&hB[(src0 + m16) * 80 + quad * 8];
          const short8 b1 = *(const short8*)&hB[(src0 + m16) * 80 + 32 + quad * 8];
          f32x4 acc = {0.f, 0.f, 0.f, 0.f};
          acc = __builtin_amdgcn_mfma_f32_16x16x32_bf16(a0, b0, acc, 0, 0, 0);
          acc = __builtin_amdgcn_mfma_f32_16x16x32_bf16(a1, b1, acc, 0, 0, 0);
#pragma unroll
          for (int r = 0; r < 4; ++r) {
            int row = m0 + quad * 4 + r;
            SS[row * 128 + ((src0 + m16) ^ ((row & 7) << 4))] = acc[r];
          }
        }
      }
      __syncthreads();

      // ---- P2: deposit v frags -> Vt (AV region, bf16, transposed); alpha + segment max
#pragma unroll
      for (int r = 0; r < 4; ++r) AV[(m16) * 136 + m0 + quad * 4 + r] = f2bf(vf0[r]);
#pragma unroll
      for (int r = 0; r < 4; ++r) AV[(16 + m16) * 136 + m0 + quad * 4 + r] = f2bf(vf1[r]);
#pragma unroll
      for (int r = 0; r < 4; ++r) AV[(32 + m16) * 136 + m0 + quad * 4 + r] = f2bf(vf2[r]);
#pragma unroll
      for (int r = 0; r < 4; ++r) AV[(48 + m16) * 136 + m0 + quad * 4 + r] = f2bf(vf3[r]);
      float aA, aB, aC = 0.f;
      {
        int src = edA & 255, dst = edA >> 8;
        float4 r80 = *(const float4*)&r8L[dst * 8];
        float4 r81 = *(const float4*)&r8L[dst * 8 + 4];
        aA = SS[dst * 128 + (src ^ ((dst & 7) << 4))] + cDL[dst] + cSL[src]
           + eaA0.x * r80.x + eaA0.y * r80.y + eaA0.z * r80.z + eaA0.w * r80.w
           + eaA1.x * r81.x + eaA1.y * r81.y + eaA1.z * r81.z + eaA1.w * r81.w;
        atomicMax(&mL[dst], encf(aA));
      }
      {
        int src = edB & 255, dst = edB >> 8;
        float4 r80 = *(const float4*)&r8L[dst * 8];
        float4 r81 = *(const float4*)&r8L[dst * 8 + 4];
        aB = SS[dst * 128 + (src ^ ((dst & 7) << 4))] + cDL[dst] + cSL[src]
           + eaB0.x * r80.x + eaB0.y * r80.y + eaB0.z * r80.z + eaB0.w * r80.w
           + eaB1.x * r81.x + eaB1.y * r81.y + eaB1.z * r81.z + eaB1.w * r81.w;
        atomicMax(&mL[dst], encf(aB));
      }
      if (hasC) {
        int src = edC & 255, dst = edC >> 8;
        float4 r80 = *(const float4*)&r8L[dst * 8];
        float4 r81 = *(const float4*)&r8L[dst * 8 + 4];
        aC = SS[dst * 128 + (src ^ ((dst & 7) << 4))] + cDL[dst] + cSL[src]
           + eaC0.x * r80.x + eaC0.y * r80.y + eaC0.z * r80.z + eaC0.w * r80.w
           + eaC1.x * r81.x + eaC1.y * r81.y + eaC1.z * r81.z + eaC1.w * r81.w;
        atomicMax(&mL[dst], encf(aC));
      }
      __syncthreads();

      // ---- P3: zero SS; exp + segment sum (alpha stays in regs)
      for (int idx = tid; idx < 4096; idx += 512)
        *(float4*)&SS[idx * 4] = make_float4(0.f, 0.f, 0.f, 0.f);
      {
        int dst = edA >> 8;
        aA = expf(aA - decf(mL[dst]));
        atomicAdd(&sL[dst], aA);
      }
      {
        int dst = edB >> 8;
        aB = expf(aB - decf(mL[dst]));
        atomicAdd(&sL[dst], aB);
      }
      if (hasC) {
        int dst = edC >> 8;
        aC = expf(aC - decf(mL[dst]));
        atomicAdd(&sL[dst], aC);
      }
      __syncthreads();

      // ---- P4: scatter normalized weights into Wmat(fp32, swizzled); accumulate t8
      {
        int src = edA & 255, dst = edA >> 8;
        float w = aA / fmaxf(sL[dst], 1e-16f);
        atomicAdd(&SS[dst * 128 + (src ^ ((dst & 7) << 4))], w);
        float* t8 = &t8L[dst * 9];
        atomicAdd(t8 + 0, w * eaA0.x); atomicAdd(t8 + 1, w * eaA0.y);
        atomicAdd(t8 + 2, w * eaA0.z); atomicAdd(t8 + 3, w * eaA0.w);
        atomicAdd(t8 + 4, w * eaA1.x); atomicAdd(t8 + 5, w * eaA1.y);
        atomicAdd(t8 + 6, w * eaA1.z); atomicAdd(t8 + 7, w * eaA1.w);
      }
      {
        int src = edB & 255, dst = edB >> 8;
        float w = aB / fmaxf(sL[dst], 1e-16f);
        atomicAdd(&SS[dst * 128 + (src ^ ((dst & 7) << 4))], w);
        float* t8 = &t8L[dst * 9];
        atomicAdd(t8 + 0, w * eaB0.x); atomicAdd(t8 + 1, w * eaB0.y);
        atomicAdd(t8 + 2, w * eaB0.z); atomicAdd(t8 + 3, w * eaB0.w);
        atomicAdd(t8 + 4, w * eaB1.x); atomicAdd(t8 + 5, w * eaB1.y);
        atomicAdd(t8 + 6, w * eaB1.z); atomicAdd(t8 + 7, w * eaB1.w);
      }
      if (hasC) {
        int src = edC & 255, dst = edC >> 8;
        float w = aC / fmaxf(sL[dst], 1e-16f);
        atomicAdd(&SS[dst * 128 + (src ^ ((dst & 7) << 4))], w);
        float* t8 = &t8L[dst * 9];
        atomicAdd(t8 + 0, w * eaC0.x); atomicAdd(t8 + 1, w * eaC0.y);
        atomicAdd(t8 + 2, w * eaC0.z); atomicAdd(t8 + 3, w * eaC0.w);
        atomicAdd(t8 + 4, w * eaC1.x); atomicAdd(t8 + 5, w * eaC1.y);
        atomicAdd(t8 + 6, w * eaC1.z); atomicAdd(t8 + 7, w * eaC1.w);
      }
      __syncthreads();

      // ---- P4.5: repack Wmat fp32(swizzled) -> bf16 stride 136 in place (32 vals/thread)
      {
        float vals0[16], vals1[16];
        int d0 = tid >> 3, s0 = (tid & 7) * 16;            // slice 0: rows 0..63
        int d1 = 64 + (tid >> 3), s1 = s0;                 // slice 1: rows 64..127
        int base0 = d0 * 128 + (s0 ^ ((d0 & 7) << 4));
        int base1 = d1 * 128 + (s1 ^ ((d1 & 7) << 4));
#pragma unroll
        for (int i = 0; i < 16; ++i) vals0[i] = SS[base0 + i];
#pragma unroll
        for (int i = 0; i < 16; ++i) vals1[i] = SS[base1 + i];
        __syncthreads();
        unsigned short* Wu = (unsigned short*)SS;
#pragma unroll
        for (int g4 = 0; g4 < 2; ++g4) {
          uint4 u;
          u.x = f2bf(vals0[g4 * 8 + 0]) | ((unsigned)f2bf(vals0[g4 * 8 + 1]) << 16);
          u.y = f2bf(vals0[g4 * 8 + 2]) | ((unsigned)f2bf(vals0[g4 * 8 + 3]) << 16);
          u.z = f2bf(vals0[g4 * 8 + 4]) | ((unsigned)f2bf(vals0[g4 * 8 + 5]) << 16);
          u.w = f2bf(vals0[g4 * 8 + 6]) | ((unsigned)f2bf(vals0[g4 * 8 + 7]) << 16);
          *(uint4*)&Wu[d0 * 136 + s0 + g4 * 8] = u;
        }
#pragma unroll
        for (int g4 = 0; g4 < 2; ++g4) {
          uint4 u;
          u.x = f2bf(vals1[g4 * 8 + 0]) | ((unsigned)f2bf(vals1[g4 * 8 + 1]) << 16);
          u.y = f2bf(vals1[g4 * 8 + 2]) | ((unsigned)f2bf(vals1[g4 * 8 + 3]) << 16);
          u.z = f2bf(vals1[g4 * 8 + 4]) | ((unsigned)f2bf(vals1[g4 * 8 + 5]) << 16);
          u.w = f2bf(vals1[g4 * 8 + 6]) | ((unsigned)f2bf(vals1[g4 * 8 + 7]) << 16);
          *(uint4*)&Wu[d1 * 136 + s1 + g4 * 8] = u;
        }
      }
      __syncthreads();

      // ---- P5: accP5 += Wmat@Vt (MFMA, 4 col-tiles) + t8@G + sw*bb ; prefetch next WT/Wskip
      {
        int nlh = l * 4 + h + 1;
        if (nlh < 16) {
          const uint4* wsrc = (const uint4*)(WcatT + (size_t)nlh * (WC2 * 64));
          wpA = wsrc[tid];
          wpB = wsrc[512 + tid];
          if (hasC) wpC = wsrc[1024 + tid];
        }
        if (h == 3) {
          wsk0 = ((const float4*)(Wskip + (size_t)l * 4096))[tid];
          wsk1 = ((const float4*)(Wskip + (size_t)l * 4096))[512 + tid];
        }

        const unsigned short* Wu = (const unsigned short*)SS;
        short8 a_[4];
#pragma unroll
        for (int ks = 0; ks < 4; ++ks)
          a_[ks] = *(const short8*)&Wu[(m0 + m16) * 136 + ks * 32 + quad * 8];
#pragma unroll
        for (int t2 = 0; t2 < 4; ++t2) {
          int c0 = t2 * 16;
          f32x4 acc = (t2 == 0) ? accP5_0 : (t2 == 1) ? accP5_1 : (t2 == 2) ? accP5_2 : accP5_3;
#pragma unroll
          for (int ks = 0; ks < 4; ++ks) {
            const short8 b = *(const short8*)&AV[(c0 + m16) * 136 + ks * 32 + quad * 8];
            acc = __builtin_amdgcn_mfma_f32_16x16x32_bf16(a_[ks], b, acc, 0, 0, 0);
          }
          int col = c0 + m16;
          float bbv = bbuf[l * 256 + h * 64 + col];
          float gcol[8];
#pragma unroll
          for (int a8 = 0; a8 < 8; ++a8) gcol[a8] = GhL[a8 * 64 + col];
#pragma unroll
          for (int r = 0; r < 4; ++r) {
            int row = m0 + quad * 4 + r;
            float add = (sL[row] > 0.f) ? bbv : 0.f;
#pragma unroll
            for (int a8 = 0; a8 < 8; ++a8) add += t8L[row * 9 + a8] * gcol[a8];
            acc[r] += add;
          }
          if (t2 == 0) accP5_0 = acc;
          else if (t2 == 1) accP5_1 = acc;
          else if (t2 == 2) accP5_2 = acc;
          else accP5_3 = acc;
        }
      }
    }  // heads

    // ---- update: out = 0.25*acc + h@Wskip+bskip ; vemb ; h += out (all in LDS)
    __syncthreads();
    *(float4*)&SS[tid * 4] = wsk0;         // Wskip_l -> SS[0..2048)
    *(float4*)&SS[2048 + tid * 4] = wsk1;  // Wskip_l -> SS[2048..4096)
    __syncthreads();
    {
      float sk[4][4];
#pragma unroll
      for (int t2 = 0; t2 < 4; ++t2) {
        int col = t2 * 16 + m16;
        float bsv = bskip[l * 64 + col];
#pragma unroll
        for (int r = 0; r < 4; ++r) {
          int row = m0 + quad * 4 + r;
          float s = bsv;
#pragma unroll 8
          for (int d = 0; d < 64; ++d) s += h32[row * 68 + d] * SS[d * 64 + col];
          sk[t2][r] = s;
        }
      }
      __syncthreads();  // all h32 reads done before in-place writes
#pragma unroll
      for (int t2 = 0; t2 < 4; ++t2) {
        int col = t2 * 16 + m16;
#pragma unroll
        for (int r = 0; r < 4; ++r) {
          int row = m0 + quad * 4 + r;
          float av = (t2 == 0) ? accP5_0[r] : (t2 == 1) ? accP5_1[r]
                   : (t2 == 2) ? accP5_2[r] : accP5_3[r];
          float outv = av * 0.25f + sk[t2][r];
          float hnew = outv + h32[row * 68 + col];
          h32[row * 68 + col] = hnew;
          if (row == 127) vembL[l * 64 + col] = outv;
        }
      }
    }
    __syncthreads();
  }  // layers

  // ---- head: pool = vemb @ W_down + b_down; out = sigmoid(pool @ W_out + b_out)
  {
    float part = 0.f;
#pragma unroll
    for (int j2 = 0; j2 < 32; ++j2) {
      int j = wv * 32 + j2;
      part += vembL[j] * Wd[j * 64 + lane];
    }
    SS[wv * 64 + lane] = part;
    __syncthreads();
    if (wv == 0) {
      float acc = bd[lane];
#pragma unroll
      for (int w2 = 0; w2 < 8; ++w2) acc += SS[w2 * 64 + lane];
      float p = acc * Wo[lane];
      p = wave_red_sum(p);
      if (lane == 63) out[g] = 1.f / (1.f + expf(-(p + bo[0])));
    }
  }
}

extern "C" void kernel_launch(void* const* d_in, const int* in_sizes, int n_in,
                              void* d_out, int out_size, void* d_ws, size_t ws_size,
                              hipStream_t stream) {
  const float* x         = (const float*)d_in[0];
  const float* edge_attr = (const float*)d_in[1];
  const int*   ei        = (const int*)d_in[2];
  const float* W_node = (const float*)d_in[4];
  const float* b_node = (const float*)d_in[5];
  const float* W_edge = (const float*)d_in[6];
  const float* b_edge = (const float*)d_in[7];
  const float* Wq = (const float*)d_in[8];
  const float* bq = (const float*)d_in[9];
  const float* Wk = (const float*)d_in[10];
  const float* bk = (const float*)d_in[11];
  const float* Wv = (const float*)d_in[12];
  const float* bv = (const float*)d_in[13];
  const float* We = (const float*)d_in[14];
  const float* be = (const float*)d_in[15];
  const float* Wskip = (const float*)d_in[16];
  const float* bskip = (const float*)d_in[17];
  const float* W_down = (const float*)d_in[18];
  const float* b_down = (const float*)d_in[19];
  const float* W_out  = (const float*)d_in[20];
  const float* b_out  = (const float*)d_in[21];
  float* out = (float*)d_out;

  // workspace carve (~341 KB)
  float* p = (float*)d_ws;
  float* Gbuf  = p; p += 8192;
  float* bbuf  = p; p += 1024;
  float* bcatT = p; p += 16 * WC2;                 // 2304 floats
  unsigned short* WcatT = (unsigned short*)p;      // 16*144*64 bf16 = 294912 B (16B-aligned)

  k_prep2<<<36, 256, 0, stream>>>(We, be, W_edge, b_edge, Gbuf, bbuf);
  k_prepW<<<(16 * WC2 * 64) / 256, 256, 0, stream>>>(Wq, bq, Wk, bk, Wv, bv, Gbuf, bbuf,
                                                     WcatT, bcatT);
  k_fused<<<256, 512, 0, stream>>>(x, W_node, b_node, WcatT, bcatT, edge_attr, ei,
                                   Gbuf, bbuf, Wskip, bskip, W_down, b_down, W_out, b_out,
                                   out);
}